// Round 6
// baseline (25.470 us; speedup 1.0000x reference)
//
#include <hip/hip_runtime.h>

#define BATCH   8192
#define NNEIGH  64
#define FEAT    128
#define EMBED   64
#define ROWS    4           // batch rows per block -> grid 2048 (2 generations/CU)
#define CATP    260         // padded cat row stride (floats): b128-aligned, bank-spread
#define EPAD    68          // padded s_part stride (68*4B = 17*16B)
#define KCH     8           // split-k chunks of 32

// 256 threads = 4 waves, 4 rows per block, grid = 2048.
// Wave w owns row w end-to-end (no barrier until matmul):
//   P1: self-feat float2/lane (full row in 1 instr) issued first.
//   P2: 64-lane bitonic sort, stable (value,index) lexicographic order.
//   P3: gather: 17 independent full-row loads (64 x float2), ids via __shfl.
//   P4: split-k matmul: thread = (q cols, rp row-pair, ks k-chunk of 32);
//       W float4 dedup'd across row-pair lanes; LDS k-reduce + ReLU.
// ~13 KB LDS/block -> up to 8 blocks/CU co-resident; generations pipeline.
__global__ __launch_bounds__(256, 4) void intra_agg_kernel(
    const float* __restrict__ feat,    // [N_NODES, 128]
    const float* __restrict__ W,       // [256, 64]
    const int*   __restrict__ nodes,   // [B]
    const float* __restrict__ bscore,  // [B, 2]
    const float* __restrict__ nscore,  // [B, 64, 2]
    const int*   __restrict__ nids,    // [B, 64]
    const int*   __restrict__ ns_ptr,  // scalar num_sample (16)
    float*       __restrict__ out)     // [B*64] to_feats ++ [B*ns] samp_scores
{
    const int b0   = blockIdx.x * ROWS;
    const int tid  = threadIdx.x;
    const int lane = tid & 63;
    const int wave = tid >> 6;
    const int ns   = *ns_ptr;

    __shared__ float s_cat[ROWS * CATP];
    __shared__ float s_part[KCH][ROWS][EPAD];

    const int row = b0 + wave;

    // ---- earliest: self features (in flight during sort) ------------------
    const float2 self2 = *(const float2*)&feat[(size_t)nodes[row] * FEAT + lane * 2];

    // ---- sort input -------------------------------------------------------
    const float  ctr = bscore[row * 2];
    const float2 sc  = *(const float2*)&nscore[(size_t)(row * NNEIGH + lane) * 2];
    float d   = fabsf(ctr - sc.x);
    int   idx = lane;

    // ---- 64-lane bitonic sort (stable lexicographic) ----------------------
    #pragma unroll
    for (int k = 2; k <= 64; k <<= 1) {
        #pragma unroll
        for (int j = k >> 1; j > 0; j >>= 1) {
            const float od = __shfl_xor(d, j);
            const int   oi = __shfl_xor(idx, j);
            const bool up    = ((lane & k) == 0);
            const bool lower = ((lane & j) == 0);
            // lexicographic (value, index) => jax stable top_k tie-break
            const bool oless = (od < d) || (od == d && oi < idx);
            if ((lower == up) ? oless : !oless) { d = od; idx = oi; }
        }
    }

    // ---- samp_scores + selected ids ---------------------------------------
    int gid = 0;
    if (lane < ns) {
        out[(size_t)BATCH * EMBED + (size_t)row * ns + lane] = d;
        gid = nids[row * NNEIGH + idx];
    }

    // ---- gather + mean: one full row per instruction (64 x float2) --------
    float2 a = make_float2(0.f, 0.f);
    if (ns == 16) {
        #pragma unroll
        for (int j = 0; j < 16; ++j) {
            const int id = __shfl(gid, j);
            const float2 v = *(const float2*)&feat[(size_t)id * FEAT + lane * 2];
            a.x += v.x; a.y += v.y;
        }
    } else {
        for (int j = 0; j < ns; ++j) {
            const int id = __shfl(gid, j);
            const float2 v = *(const float2*)&feat[(size_t)id * FEAT + lane * 2];
            a.x += v.x; a.y += v.y;
        }
    }
    const float inv_ns = 1.0f / (float)ns;
    a.x *= inv_ns; a.y *= inv_ns;

    *(float2*)&s_cat[wave * CATP + lane * 2]        = self2;   // 2-way (free)
    *(float2*)&s_cat[wave * CATP + FEAT + lane * 2] = a;
    __syncthreads();

    // ---------------- split-k matmul, (2 rows x 4 cols) tile ---------------
    {
        const int q  = tid & 15;          // 4-col group of W/out
        const int rp = (tid >> 4) & 1;    // row pair: rows rp*2, rp*2+1
        const int ks = tid >> 5;          // k-chunk of 32 (0..7)
        const int k0 = ks * 32;

        float4 acc[2];
        acc[0] = make_float4(0.f, 0.f, 0.f, 0.f);
        acc[1] = make_float4(0.f, 0.f, 0.f, 0.f);

        #pragma unroll
        for (int kk = 0; kk < 32; kk += 4) {
            const int k = k0 + kk;
            float4 cv[2];
            #pragma unroll
            for (int r = 0; r < 2; ++r)
                cv[r] = *(const float4*)&s_cat[(rp * 2 + r) * CATP + k]; // broadcast
            #pragma unroll
            for (int t = 0; t < 4; ++t) {
                const float4 w4 = *(const float4*)&W[(size_t)(k + t) * EMBED + q * 4];
                #pragma unroll
                for (int r = 0; r < 2; ++r) {
                    const float cf = (t == 0) ? cv[r].x : (t == 1) ? cv[r].y
                                   : (t == 2) ? cv[r].z : cv[r].w;
                    acc[r].x += cf * w4.x; acc[r].y += cf * w4.y;
                    acc[r].z += cf * w4.z; acc[r].w += cf * w4.w;
                }
            }
        }
        #pragma unroll
        for (int r = 0; r < 2; ++r)
            *(float4*)&s_part[ks][rp * 2 + r][q * 4] = acc[r];
    }
    __syncthreads();

    // ---------------- reduce k-chunks, ReLU, store -------------------------
    if (tid < ROWS * 16) {
        const int r2 = tid >> 4;          // 0..3
        const int q  = tid & 15;
        float4 o = make_float4(0.f, 0.f, 0.f, 0.f);
        #pragma unroll
        for (int p = 0; p < KCH; ++p) {
            const float4 v = *(const float4*)&s_part[p][r2][q * 4];
            o.x += v.x; o.y += v.y; o.z += v.z; o.w += v.w;
        }
        o.x = fmaxf(o.x, 0.f); o.y = fmaxf(o.y, 0.f);
        o.z = fmaxf(o.z, 0.f); o.w = fmaxf(o.w, 0.f);
        *(float4*)&out[(size_t)(b0 + r2) * EMBED + q * 4] = o;
    }
}

extern "C" void kernel_launch(void* const* d_in, const int* in_sizes, int n_in,
                              void* d_out, int out_size, void* d_ws, size_t ws_size,
                              hipStream_t stream) {
    const float* feat   = (const float*)d_in[0];
    const float* W      = (const float*)d_in[1];
    const int*   nodes  = (const int*)d_in[2];
    const float* bscore = (const float*)d_in[3];
    const float* nscore = (const float*)d_in[4];
    const int*   nids   = (const int*)d_in[5];
    const int*   nsamp  = (const int*)d_in[6];
    float* out = (float*)d_out;

    intra_agg_kernel<<<BATCH / ROWS, 256, 0, stream>>>(feat, W, nodes, bscore,
                                                       nscore, nids, nsamp, out);
}

// Round 7
// 24.065 us; speedup vs baseline: 1.0584x; 1.0584x over previous
//
#include <hip/hip_runtime.h>

#define BATCH   8192
#define NNEIGH  64
#define FEAT    128
#define EMBED   64
#define ROWS    8           // batch rows per block -> grid 1024
#define CATP    260         // padded cat row stride (floats): b128-aligned, bank-spread
#define EPAD    68          // padded s_part stride (68*4B = 17*16B)
#define KCH     8           // split-k chunks of 32

// 256 threads = 4 waves, 8 rows per block. Wave w owns rows 2w, 2w+1.
//   P1: self-feat float4 + both rows' nids (coalesced) issued first.
//   P2: rank selection: 63 INDEPENDENT xor-shuffles of d per row; tie-break
//       partner index is lane^m (free). rank = output position (jax stable
//       top_k semantics). No dependent shuffle chain.
//   P3: ds_permute pushes selected ids to rank order; samp_scores scattered
//       within one cache line per row.
//   P4: gather: 16 x 1KB instructions (lanes 0-31 row A, 32-63 row B).
//   P5: split-k matmul (4x4 tile), LDS k-reduce + ReLU (R5-proven).
__global__ __launch_bounds__(256, 4) void intra_agg_kernel(
    const float* __restrict__ feat,    // [N_NODES, 128]
    const float* __restrict__ W,       // [256, 64]
    const int*   __restrict__ nodes,   // [B]
    const float* __restrict__ bscore,  // [B, 2]
    const float* __restrict__ nscore,  // [B, 64, 2]
    const int*   __restrict__ nids,    // [B, 64]
    const int*   __restrict__ ns_ptr,  // scalar num_sample (16)
    float*       __restrict__ out)     // [B*64] to_feats ++ [B*ns] samp_scores
{
    const int b0   = blockIdx.x * ROWS;
    const int tid  = threadIdx.x;
    const int lane = tid & 63;
    const int wave = tid >> 6;
    const int ns   = *ns_ptr;

    __shared__ float s_cat[ROWS * CATP];
    __shared__ float s_part[KCH][ROWS][EPAD];

    const int r0   = wave * 2;        // wave's first local row
    const int half = lane >> 5;       // 0 -> row A, 1 -> row B
    const int c    = lane & 31;       // float4 chunk within 128-wide row
    const int rA   = b0 + r0;
    const int rB   = rA + 1;

    // ---- earliest independent loads (in flight during ranking) ------------
    const int    selfnode = nodes[rA + half];
    const float4 self4    = *(const float4*)&feat[(size_t)selfnode * FEAT + c * 4];
    const int    nidA     = nids[rA * NNEIGH + lane];   // coalesced 256B
    const int    nidB     = nids[rB * NNEIGH + lane];

    // ---- score diffs ------------------------------------------------------
    const float  ctrA = bscore[rA * 2];
    const float  ctrB = bscore[rB * 2];
    const float2 scA  = *(const float2*)&nscore[(size_t)(rA * NNEIGH + lane) * 2];
    const float2 scB  = *(const float2*)&nscore[(size_t)(rB * NNEIGH + lane) * 2];
    const float  dA   = fabsf(ctrA - scA.x);
    const float  dB   = fabsf(ctrB - scB.x);

    // ---- rank = #elements lexicographically smaller (stable top_k order) --
    // 63 independent shuffles per row; partner's original index = lane^m.
    int rankA = 0, rankB = 0;
    #pragma unroll
    for (int m = 1; m < 64; ++m) {
        const float oA = __shfl_xor(dA, m);
        const float oB = __shfl_xor(dB, m);
        const int   ol = lane ^ m;
        rankA += (int)((oA < dA) | ((oA == dA) & (ol < lane)));
        rankB += (int)((oB < dB) | ((oB == dB) & (ol < lane)));
    }

    // ---- samp_scores: position = rank (16 x 4B within one 64B line) -------
    if (rankA < ns) out[(size_t)BATCH * EMBED + (size_t)rA * ns + rankA] = dA;
    if (rankB < ns) out[(size_t)BATCH * EMBED + (size_t)rB * ns + rankB] = dB;

    // ---- push nids to rank order: lane j holds rank-j id ------------------
    const int gidA = __builtin_amdgcn_ds_permute(rankA << 2, nidA);
    const int gidB = __builtin_amdgcn_ds_permute(rankB << 2, nidB);

    // ---- gather + mean: both rows per instruction (1KB), ids via shfl -----
    float4 a = make_float4(0.f, 0.f, 0.f, 0.f);
    if (ns == 16) {
        #pragma unroll
        for (int j = 0; j < 16; ++j) {
            const int iA = __shfl(gidA, j);
            const int iB = __shfl(gidB, j);
            const int id = half ? iB : iA;
            const float4 v = *(const float4*)&feat[(size_t)id * FEAT + c * 4];
            a.x += v.x; a.y += v.y; a.z += v.z; a.w += v.w;
        }
    } else {
        for (int j = 0; j < ns; ++j) {
            const int iA = __shfl(gidA, j);
            const int iB = __shfl(gidB, j);
            const int id = half ? iB : iA;
            const float4 v = *(const float4*)&feat[(size_t)id * FEAT + c * 4];
            a.x += v.x; a.y += v.y; a.z += v.z; a.w += v.w;
        }
    }
    const float inv_ns = 1.0f / (float)ns;
    a.x *= inv_ns; a.y *= inv_ns; a.z *= inv_ns; a.w *= inv_ns;

    {
        const int r = r0 + half;
        *(float4*)&s_cat[r * CATP + c * 4]        = self4;  // conflict-free b128
        *(float4*)&s_cat[r * CATP + FEAT + c * 4] = a;
    }
    __syncthreads();

    // ---------------- split-k matmul, (4 rows x 4 cols) tile ---------------
    {
        const int q  = tid & 15;          // 4-col group of W/out
        const int rq = (tid >> 4) & 1;    // row-quad: rows rq*4 .. rq*4+3
        const int ks = tid >> 5;          // k-chunk of 32 (0..7)
        const int k0 = ks * 32;

        float4 acc[4];
        #pragma unroll
        for (int r = 0; r < 4; ++r) acc[r] = make_float4(0.f, 0.f, 0.f, 0.f);

        #pragma unroll
        for (int kk = 0; kk < 32; kk += 4) {
            const int k = k0 + kk;
            float4 cv[4];
            #pragma unroll
            for (int r = 0; r < 4; ++r)
                cv[r] = *(const float4*)&s_cat[(rq * 4 + r) * CATP + k]; // broadcast
            #pragma unroll
            for (int t = 0; t < 4; ++t) {
                const float4 w4 = *(const float4*)&W[(size_t)(k + t) * EMBED + q * 4];
                #pragma unroll
                for (int r = 0; r < 4; ++r) {
                    const float cf = (t == 0) ? cv[r].x : (t == 1) ? cv[r].y
                                   : (t == 2) ? cv[r].z : cv[r].w;
                    acc[r].x += cf * w4.x; acc[r].y += cf * w4.y;
                    acc[r].z += cf * w4.z; acc[r].w += cf * w4.w;
                }
            }
        }
        #pragma unroll
        for (int r = 0; r < 4; ++r)
            *(float4*)&s_part[ks][rq * 4 + r][q * 4] = acc[r];
    }
    __syncthreads();

    // ---------------- reduce k-chunks, ReLU, store -------------------------
    if (tid < ROWS * 16) {
        const int r2 = tid >> 4;          // 0..7
        const int q  = tid & 15;
        float4 o = make_float4(0.f, 0.f, 0.f, 0.f);
        #pragma unroll
        for (int p = 0; p < KCH; ++p) {
            const float4 v = *(const float4*)&s_part[p][r2][q * 4];
            o.x += v.x; o.y += v.y; o.z += v.z; o.w += v.w;
        }
        o.x = fmaxf(o.x, 0.f); o.y = fmaxf(o.y, 0.f);
        o.z = fmaxf(o.z, 0.f); o.w = fmaxf(o.w, 0.f);
        *(float4*)&out[(size_t)(b0 + r2) * EMBED + q * 4] = o;
    }
}

extern "C" void kernel_launch(void* const* d_in, const int* in_sizes, int n_in,
                              void* d_out, int out_size, void* d_ws, size_t ws_size,
                              hipStream_t stream) {
    const float* feat   = (const float*)d_in[0];
    const float* W      = (const float*)d_in[1];
    const int*   nodes  = (const int*)d_in[2];
    const float* bscore = (const float*)d_in[3];
    const float* nscore = (const float*)d_in[4];
    const int*   nids   = (const int*)d_in[5];
    const int*   nsamp  = (const int*)d_in[6];
    float* out = (float*)d_out;

    intra_agg_kernel<<<BATCH / ROWS, 256, 0, stream>>>(feat, W, nodes, bscore,
                                                       nscore, nids, nsamp, out);
}